// Round 1
// baseline (3261.214 us; speedup 1.0000x reference)
//
#include <hip/hip_runtime.h>

#define DIM 128   // D_IN == D_OUT == 128

// ---------------- degree / normalization ----------------

__global__ void k_init_deg(float* __restrict__ deg, int n) {
    int i = blockIdx.x * blockDim.x + threadIdx.x;
    if (i < n) deg[i] = 1.0f;   // self loop
}

__global__ void k_count(const int* __restrict__ dst, float* __restrict__ deg, int ne) {
    int i = blockIdx.x * blockDim.x + threadIdx.x;
    if (i < ne) atomicAdd(&deg[dst[i]], 1.0f);
}

__global__ void k_dinv(float* __restrict__ deg, int n) {
    int i = blockIdx.x * blockDim.x + threadIdx.x;
    if (i < n) deg[i] = rsqrtf(deg[i]);   // deg >= 1 always (self loop)
}

// ---------------- propagation ----------------

// Hn[i] = dinv[i]^2 * Hc[i]  (self-loop term; also fully initializes Hn)
__global__ void k_self(const float* __restrict__ Hc, const float* __restrict__ dinv,
                       float* __restrict__ Hn, int n) {
    int i = blockIdx.x * blockDim.x + threadIdx.x;   // over n * (DIM/4)
    int total = n * (DIM / 4);
    if (i >= total) return;
    int node = i >> 5;                                // i / (DIM/4), DIM=128
    float w = dinv[node];
    w *= w;
    float4 v = ((const float4*)Hc)[i];
    v.x *= w; v.y *= w; v.z *= w; v.w *= w;
    ((float4*)Hn)[i] = v;
}

// Hn[dst] += dinv[src]*dinv[dst] * Hc[src]; 32 lanes per edge, float4 each
__global__ void k_scatter(const int* __restrict__ src, const int* __restrict__ dst,
                          const float* __restrict__ dinv,
                          const float* __restrict__ Hc, float* __restrict__ Hn, int ne) {
    int tid = blockIdx.x * blockDim.x + threadIdx.x;
    int e = tid >> 5;
    if (e >= ne) return;
    int lane = tid & 31;
    int s = src[e], t = dst[e];
    float w = dinv[s] * dinv[t];
    float4 v = ((const float4*)(Hc + (size_t)s * DIM))[lane];
    float* o = Hn + (size_t)t * DIM + lane * 4;
    atomicAdd(o + 0, w * v.x);
    atomicAdd(o + 1, w * v.y);
    atomicAdd(o + 2, w * v.z);
    atomicAdd(o + 3, w * v.w);
}

// ---------------- epilogue: out = H @ W^T + b ----------------
// W staged TRANSPOSED in LDS so lane j reads Wt[d*128 + j] (conflict-free).

__global__ __launch_bounds__(256) void k_gemm(const float* __restrict__ H,
                                              const float* __restrict__ W,
                                              const float* __restrict__ b,
                                              float* __restrict__ out, int n) {
    __shared__ float Wt[DIM * DIM];   // 64 KiB: Wt[d*DIM + j] = W[j*DIM + d]
    int tid = threadIdx.x;
    for (int idx = tid; idx < DIM * DIM; idx += 256) {
        int j = idx >> 7;
        int d = idx & (DIM - 1);
        Wt[d * DIM + j] = W[idx];
    }
    __syncthreads();

    int j  = tid & (DIM - 1);
    int rh = tid >> 7;               // 0 or 1: two rows in flight per iteration
    float bj = b[j];
    int row0 = blockIdx.x * 16;

    for (int r = rh; r < 16; r += 2) {
        int row = row0 + r;
        if (row >= n) continue;
        const float* h = H + (size_t)row * DIM;
        float acc = bj;
        #pragma unroll
        for (int d = 0; d < DIM; d += 4) {
            float4 hv = *(const float4*)(h + d);   // same addr across lanes -> cache broadcast
            acc = fmaf(hv.x, Wt[(d + 0) * DIM + j], acc);
            acc = fmaf(hv.y, Wt[(d + 1) * DIM + j], acc);
            acc = fmaf(hv.z, Wt[(d + 2) * DIM + j], acc);
            acc = fmaf(hv.w, Wt[(d + 3) * DIM + j], acc);
        }
        out[(size_t)row * DIM + j] = acc;
    }
}

// ---------------- launch ----------------

extern "C" void kernel_launch(void* const* d_in, const int* in_sizes, int n_in,
                              void* d_out, int out_size, void* d_ws, size_t ws_size,
                              hipStream_t stream) {
    // inputs: V(int, unused), E(int 2 x ne), X(f32 n x 128), W(f32 128 x 128), b(f32 128)
    const int*   E = (const int*)d_in[1];
    const float* X = (const float*)d_in[2];
    const float* W = (const float*)d_in[3];
    const float* b = (const float*)d_in[4];

    int n  = in_sizes[0];
    int ne = in_sizes[1] / 2;
    const int* src = E;
    const int* dst = E + ne;

    float* dinv = (float*)d_ws;                          // n floats
    float* Hws  = (float*)((char*)d_ws + 262144);        // n*128 floats
    float* Hout = (float*)d_out;                         // n*128 floats (doubles as H buffer)

    const int T = 256;
    int gN  = (n + T - 1) / T;
    int gE  = (ne + T - 1) / T;
    int gNV = (n * (DIM / 4) + T - 1) / T;
    int gEV = (ne * 32 + T - 1) / T;

    // normalization
    k_init_deg<<<gN, T, 0, stream>>>(dinv, n);
    k_count<<<gE, T, 0, stream>>>(dst, dinv, ne);
    k_dinv<<<gN, T, 0, stream>>>(dinv, n);

    // hop 1: X -> Hws
    k_self<<<gNV, T, 0, stream>>>(X, dinv, Hws, n);
    k_scatter<<<gEV, T, 0, stream>>>(src, dst, dinv, X, Hws, ne);
    // hop 2: Hws -> Hout
    k_self<<<gNV, T, 0, stream>>>(Hws, dinv, Hout, n);
    k_scatter<<<gEV, T, 0, stream>>>(src, dst, dinv, Hws, Hout, ne);
    // hop 3: Hout -> Hws
    k_self<<<gNV, T, 0, stream>>>(Hout, dinv, Hws, n);
    k_scatter<<<gEV, T, 0, stream>>>(src, dst, dinv, Hout, Hws, ne);

    // epilogue: Hout = Hws @ W^T + b
    k_gemm<<<(n + 15) / 16, 256, 0, stream>>>(Hws, W, b, Hout, n);
}

// Round 2
// 468.336 us; speedup vs baseline: 6.9634x; 6.9634x over previous
//
#include <hip/hip_runtime.h>

#define DIM 128   // D_IN == D_OUT == 128

// ---------------- CSR build ----------------

__global__ void k_count(const int* __restrict__ dst, int* __restrict__ cnt, int ne) {
    int i = blockIdx.x * blockDim.x + threadIdx.x;
    if (i < ne) atomicAdd(&cnt[dst[i]], 1);
}

__global__ void k_dinv(const int* __restrict__ cnt, float* __restrict__ dinv, int n) {
    int i = blockIdx.x * blockDim.x + threadIdx.x;
    if (i < n) dinv[i] = rsqrtf((float)cnt[i] + 1.0f);   // +1 self loop
}

// single-block exclusive scan: rowptr[0..n] from cnt[0..n-1]
__global__ __launch_bounds__(1024) void k_scan(const int* __restrict__ cnt,
                                               int* __restrict__ rowptr, int n) {
    __shared__ int sums[1024];
    int t = threadIdx.x;
    int chunk = (n + 1023) >> 10;
    int lo = t * chunk, hi = min(lo + chunk, n);
    int s = 0;
    for (int i = lo; i < hi; ++i) s += cnt[i];
    sums[t] = s;
    __syncthreads();
    for (int off = 1; off < 1024; off <<= 1) {
        int v = (t >= off) ? sums[t - off] : 0;
        __syncthreads();
        if (t >= off) sums[t] += v;
        __syncthreads();
    }
    int run = (t > 0) ? sums[t - 1] : 0;
    for (int i = lo; i < hi; ++i) { rowptr[i] = run; run += cnt[i]; }
    if (t == 0) rowptr[n] = sums[1023];
}

// bin edges by dst, consuming cnt down to 0
__global__ void k_bin(const int* __restrict__ src, const int* __restrict__ dst,
                      int* __restrict__ cnt, const int* __restrict__ rowptr,
                      int* __restrict__ col, int ne) {
    int e = blockIdx.x * blockDim.x + threadIdx.x;
    if (e >= ne) return;
    int t = dst[e];
    int pos = rowptr[t] + atomicSub(&cnt[t], 1) - 1;
    col[pos] = src[e];
}

// ---------------- pull-based propagation (no atomics) ----------------
// H'[t] = dinv[t] * ( sum_e dinv[src_e]*H[src_e]  +  dinv[t]*H[t] )
// one 64-lane wave per node, float2 per lane (512 B per row, coalesced)

__global__ __launch_bounds__(256) void k_pull(const int* __restrict__ rowptr,
                                              const int* __restrict__ col,
                                              const float* __restrict__ dinv,
                                              const float* __restrict__ Hc,
                                              float* __restrict__ Hn, int n) {
    int wid = (blockIdx.x * blockDim.x + threadIdx.x) >> 6;
    if (wid >= n) return;
    int lane = threadIdx.x & 63;
    const float2* base = (const float2*)Hc;

    float dt = dinv[wid];
    float2 h = base[(size_t)wid * 64 + lane];
    float2 acc = make_float2(dt * h.x, dt * h.y);

    int e0 = rowptr[wid], e1 = rowptr[wid + 1];
    int s_next = (e0 < e1) ? col[e0] : 0;
    for (int e = e0; e < e1; ++e) {
        int s = s_next;
        if (e + 1 < e1) s_next = col[e + 1];     // prefetch next col
        float w = dinv[s];
        float2 v = base[(size_t)s * 64 + lane];
        acc.x = fmaf(w, v.x, acc.x);
        acc.y = fmaf(w, v.y, acc.y);
    }
    acc.x *= dt; acc.y *= dt;
    ((float2*)Hn)[(size_t)wid * 64 + lane] = acc;
}

// ---------------- epilogue: out = H @ W^T + b ----------------

__global__ __launch_bounds__(256) void k_gemm(const float* __restrict__ H,
                                              const float* __restrict__ W,
                                              const float* __restrict__ b,
                                              float* __restrict__ out, int n) {
    __shared__ float Wt[DIM * DIM];   // Wt[d*DIM + j] = W[j*DIM + d]
    int tid = threadIdx.x;
    for (int idx = tid; idx < DIM * DIM; idx += 256) {
        int j = idx >> 7;
        int d = idx & (DIM - 1);
        Wt[d * DIM + j] = W[idx];
    }
    __syncthreads();

    int j  = tid & (DIM - 1);
    int rh = tid >> 7;
    float bj = b[j];
    int row0 = blockIdx.x * 16;

    for (int r = rh; r < 16; r += 2) {
        int row = row0 + r;
        if (row >= n) continue;
        const float* h = H + (size_t)row * DIM;
        float acc = bj;
        #pragma unroll
        for (int d = 0; d < DIM; d += 4) {
            float4 hv = *(const float4*)(h + d);
            acc = fmaf(hv.x, Wt[(d + 0) * DIM + j], acc);
            acc = fmaf(hv.y, Wt[(d + 1) * DIM + j], acc);
            acc = fmaf(hv.z, Wt[(d + 2) * DIM + j], acc);
            acc = fmaf(hv.w, Wt[(d + 3) * DIM + j], acc);
        }
        out[(size_t)row * DIM + j] = acc;
    }
}

// ---------------- launch ----------------

extern "C" void kernel_launch(void* const* d_in, const int* in_sizes, int n_in,
                              void* d_out, int out_size, void* d_ws, size_t ws_size,
                              hipStream_t stream) {
    const int*   E = (const int*)d_in[1];
    const float* X = (const float*)d_in[2];
    const float* W = (const float*)d_in[3];
    const float* b = (const float*)d_in[4];

    int n  = in_sizes[0];
    int ne = in_sizes[1] / 2;
    const int* src = E;
    const int* dst = E + ne;

    // workspace layout (bytes)
    char* ws = (char*)d_ws;
    float* dinv   = (float*)(ws + 0);                 // n f32      (<= 256 KiB)
    int*   cnt    = (int*)  (ws + 262144);            // n i32
    int*   rowptr = (int*)  (ws + 524288);            // n+1 i32
    int*   col    = (int*)  (ws + 786432);            // ne i32     (2.4 MB)
    float* Hws    = (float*)(ws + 3211264);           // n*128 f32  (25.6 MB)
    float* Hout   = (float*)d_out;

    const int T = 256;
    int gN = (n + T - 1) / T;
    int gE = (ne + T - 1) / T;
    int gW = (n * 64 + T - 1) / T;   // one wave per node

    hipMemsetAsync(cnt, 0, (size_t)n * 4, stream);
    k_count<<<gE, T, 0, stream>>>(dst, cnt, ne);
    k_dinv<<<gN, T, 0, stream>>>(cnt, dinv, n);
    k_scan<<<1, 1024, 0, stream>>>(cnt, rowptr, n);
    k_bin<<<gE, T, 0, stream>>>(src, dst, cnt, rowptr, col, ne);

    // hops: X -> Hws -> Hout -> Hws
    k_pull<<<gW, T, 0, stream>>>(rowptr, col, dinv, X,    Hws,  n);
    k_pull<<<gW, T, 0, stream>>>(rowptr, col, dinv, Hws,  Hout, n);
    k_pull<<<gW, T, 0, stream>>>(rowptr, col, dinv, Hout, Hws,  n);

    // epilogue
    k_gemm<<<(n + 15) / 16, 256, 0, stream>>>(Hws, W, b, Hout, n);
}

// Round 3
// 396.121 us; speedup vs baseline: 8.2329x; 1.1823x over previous
//
#include <hip/hip_runtime.h>

#define DIM 128   // D_IN == D_OUT == 128

// ---------------- CSR build ----------------

__global__ void k_count(const int* __restrict__ dst, int* __restrict__ cnt, int ne) {
    int i = blockIdx.x * blockDim.x + threadIdx.x;
    if (i < ne) atomicAdd(&cnt[dst[i]], 1);
}

__global__ void k_dinv(const int* __restrict__ cnt, float* __restrict__ dinv, int n) {
    int i = blockIdx.x * blockDim.x + threadIdx.x;
    if (i < n) dinv[i] = rsqrtf((float)cnt[i] + 1.0f);   // +1 self loop
}

// single-block exclusive scan: rowptr[0..n] from cnt[0..n-1]
__global__ __launch_bounds__(1024) void k_scan(const int* __restrict__ cnt,
                                               int* __restrict__ rowptr, int n) {
    __shared__ int sums[1024];
    int t = threadIdx.x;
    int chunk = (n + 1023) >> 10;
    int lo = t * chunk, hi = min(lo + chunk, n);
    int s = 0;
    for (int i = lo; i < hi; ++i) s += cnt[i];
    sums[t] = s;
    __syncthreads();
    for (int off = 1; off < 1024; off <<= 1) {
        int v = (t >= off) ? sums[t - off] : 0;
        __syncthreads();
        if (t >= off) sums[t] += v;
        __syncthreads();
    }
    int run = (t > 0) ? sums[t - 1] : 0;
    for (int i = lo; i < hi; ++i) { rowptr[i] = run; run += cnt[i]; }
    if (t == 0) rowptr[n] = sums[1023];
}

// bin edges by dst, consuming cnt down to 0
__global__ void k_bin(const int* __restrict__ src, const int* __restrict__ dst,
                      int* __restrict__ cnt, const int* __restrict__ rowptr,
                      int* __restrict__ col, int ne) {
    int e = blockIdx.x * blockDim.x + threadIdx.x;
    if (e >= ne) return;
    int t = dst[e];
    int pos = rowptr[t] + atomicSub(&cnt[t], 1) - 1;
    col[pos] = src[e];
}

// Hs0 = dinv * X (elementwise row scale), float4 over n*32
__global__ void k_prescale(const float* __restrict__ X, const float* __restrict__ dinv,
                           float* __restrict__ Hs, int n) {
    int i = blockIdx.x * blockDim.x + threadIdx.x;
    int total = n * (DIM / 4);
    if (i >= total) return;
    int node = i >> 5;
    float w = dinv[node];
    float4 v = ((const float4*)X)[i];
    v.x *= w; v.y *= w; v.z *= w; v.w *= w;
    ((float4*)Hs)[i] = v;
}

// ---------------- pull hop on pre-scaled state (no per-edge weight) ----------------
// Hs'[t] = scale(t) * ( sum_{s in N(t)} Hs[s] + Hs[t] )
// scale = dinv^2 for inner hops, dinv for the last hop.
// one 64-lane wave per node, float2 per lane; 4-edge unroll for MLP.

__global__ __launch_bounds__(256) void k_pull(const int* __restrict__ rowptr,
                                              const int* __restrict__ col,
                                              const float* __restrict__ dinv,
                                              const float* __restrict__ Hc,
                                              float* __restrict__ Hn, int n, int last) {
    int wid = (blockIdx.x * blockDim.x + threadIdx.x) >> 6;
    if (wid >= n) return;
    int lane = threadIdx.x & 63;
    const float2* __restrict__ base = (const float2*)Hc;
    size_t li = (size_t)wid * 64 + lane;

    float2 acc = base[li];                 // self term
    int e0 = rowptr[wid], e1 = rowptr[wid + 1];
    int e = e0;
    for (; e + 3 < e1; e += 4) {
        int s0 = col[e], s1 = col[e + 1], s2 = col[e + 2], s3 = col[e + 3];
        float2 a = base[(size_t)s0 * 64 + lane];
        float2 b = base[(size_t)s1 * 64 + lane];
        float2 c = base[(size_t)s2 * 64 + lane];
        float2 d = base[(size_t)s3 * 64 + lane];
        acc.x += (a.x + b.x) + (c.x + d.x);
        acc.y += (a.y + b.y) + (c.y + d.y);
    }
    for (; e < e1; ++e) {
        int s = col[e];
        float2 a = base[(size_t)s * 64 + lane];
        acc.x += a.x;
        acc.y += a.y;
    }
    float w = dinv[wid];
    float scale = last ? w : w * w;
    acc.x *= scale; acc.y *= scale;
    ((float2*)Hn)[li] = acc;
}

// ---------------- epilogue: out = H @ W^T + b ----------------
// Wt staged [d][j] in LDS (64 KiB). Wave owns 8 rows x 128 cols; lane owns a
// col pair. Per d4 step: 8 broadcast float4 H loads + 4 ds_read_b64 feed 64 FMA.

__global__ __launch_bounds__(256) void k_gemm(const float* __restrict__ H,
                                              const float* __restrict__ W,
                                              const float* __restrict__ b,
                                              float* __restrict__ out, int n) {
    __shared__ float Wt[DIM * DIM];   // Wt[d*DIM + j] = W[j*DIM + d]
    int tid = threadIdx.x;
    // staging: consecutive lanes -> consecutive j -> conflict-free LDS writes
    for (int idx = tid; idx < DIM * DIM; idx += 256) {
        int d = idx >> 7;
        int j = idx & (DIM - 1);
        Wt[d * DIM + j] = W[j * DIM + d];
    }
    __syncthreads();

    int lane = tid & 63;
    int wv   = tid >> 6;          // wave 0..3
    int j0   = lane * 2;
    int row0 = blockIdx.x * 32 + wv * 8;

    float2 bias = make_float2(b[j0], b[j0 + 1]);
    float2 acc[8];
    const float* hp[8];
    #pragma unroll
    for (int r = 0; r < 8; ++r) {
        acc[r] = bias;
        int rc = row0 + r; if (rc > n - 1) rc = n - 1;   // clamp loads; stores guarded
        hp[r] = H + (size_t)rc * DIM;
    }

    for (int d4 = 0; d4 < DIM / 4; ++d4) {
        float4 hv[8];
        #pragma unroll
        for (int r = 0; r < 8; ++r) hv[r] = *(const float4*)(hp[r] + d4 * 4);
        float2 w0 = *(const float2*)&Wt[(d4 * 4 + 0) * DIM + j0];
        float2 w1 = *(const float2*)&Wt[(d4 * 4 + 1) * DIM + j0];
        float2 w2 = *(const float2*)&Wt[(d4 * 4 + 2) * DIM + j0];
        float2 w3 = *(const float2*)&Wt[(d4 * 4 + 3) * DIM + j0];
        #pragma unroll
        for (int r = 0; r < 8; ++r) {
            acc[r].x = fmaf(hv[r].x, w0.x, acc[r].x);
            acc[r].y = fmaf(hv[r].x, w0.y, acc[r].y);
            acc[r].x = fmaf(hv[r].y, w1.x, acc[r].x);
            acc[r].y = fmaf(hv[r].y, w1.y, acc[r].y);
            acc[r].x = fmaf(hv[r].z, w2.x, acc[r].x);
            acc[r].y = fmaf(hv[r].z, w2.y, acc[r].y);
            acc[r].x = fmaf(hv[r].w, w3.x, acc[r].x);
            acc[r].y = fmaf(hv[r].w, w3.y, acc[r].y);
        }
    }

    #pragma unroll
    for (int r = 0; r < 8; ++r) {
        int row = row0 + r;
        if (row < n) *(float2*)(out + (size_t)row * DIM + j0) = acc[r];
    }
}

// ---------------- launch ----------------

extern "C" void kernel_launch(void* const* d_in, const int* in_sizes, int n_in,
                              void* d_out, int out_size, void* d_ws, size_t ws_size,
                              hipStream_t stream) {
    const int*   E = (const int*)d_in[1];
    const float* X = (const float*)d_in[2];
    const float* W = (const float*)d_in[3];
    const float* b = (const float*)d_in[4];

    int n  = in_sizes[0];
    int ne = in_sizes[1] / 2;
    const int* src = E;
    const int* dst = E + ne;

    // workspace layout (bytes)
    char* ws = (char*)d_ws;
    float* dinv   = (float*)(ws + 0);                 // n f32
    int*   cnt    = (int*)  (ws + 262144);            // n i32
    int*   rowptr = (int*)  (ws + 524288);            // n+1 i32
    int*   col    = (int*)  (ws + 786432);            // ne i32
    float* Hws    = (float*)(ws + 3211264);           // n*128 f32 (25.6 MB)
    float* Hout   = (float*)d_out;

    const int T = 256;
    int gN  = (n + T - 1) / T;
    int gE  = (ne + T - 1) / T;
    int gNV = (n * (DIM / 4) + T - 1) / T;
    int gW  = (n * 64 + T - 1) / T;   // one wave per node

    hipMemsetAsync(cnt, 0, (size_t)n * 4, stream);
    k_count<<<gE, T, 0, stream>>>(dst, cnt, ne);
    k_dinv<<<gN, T, 0, stream>>>(cnt, dinv, n);
    k_scan<<<1, 1024, 0, stream>>>(cnt, rowptr, n);
    k_bin<<<gE, T, 0, stream>>>(src, dst, cnt, rowptr, col, ne);

    // Hs0 = dinv * X  -> Hout; then hops alternate Hout/Hws
    k_prescale<<<gNV, T, 0, stream>>>(X, dinv, Hout, n);
    k_pull<<<gW, T, 0, stream>>>(rowptr, col, dinv, Hout, Hws,  n, 0);
    k_pull<<<gW, T, 0, stream>>>(rowptr, col, dinv, Hws,  Hout, n, 0);
    k_pull<<<gW, T, 0, stream>>>(rowptr, col, dinv, Hout, Hws,  n, 1);

    // epilogue: Hout = Hws @ W^T + b
    k_gemm<<<(n + 31) / 32, 256, 0, stream>>>(Hws, W, b, Hout, n);
}

// Round 4
// 346.531 us; speedup vs baseline: 9.4110x; 1.1431x over previous
//
#include <hip/hip_runtime.h>

#define DIM 128   // D_IN == D_OUT == 128

// ---------------- CSR build ----------------

__global__ void k_count(const int* __restrict__ dst, int* __restrict__ cnt, int ne) {
    int i = blockIdx.x * blockDim.x + threadIdx.x;
    if (i < ne) atomicAdd(&cnt[dst[i]], 1);
}

__global__ void k_dinv(const int* __restrict__ cnt, float* __restrict__ dinv, int n) {
    int i = blockIdx.x * blockDim.x + threadIdx.x;
    if (i < n) dinv[i] = rsqrtf((float)cnt[i] + 1.0f);   // +1 self loop
}

// single-block exclusive scan: rowptr[0..n] from cnt[0..n-1]
__global__ __launch_bounds__(1024) void k_scan(const int* __restrict__ cnt,
                                               int* __restrict__ rowptr, int n) {
    __shared__ int sums[1024];
    int t = threadIdx.x;
    int chunk = (n + 1023) >> 10;
    int lo = t * chunk, hi = min(lo + chunk, n);
    int s = 0;
    for (int i = lo; i < hi; ++i) s += cnt[i];
    sums[t] = s;
    __syncthreads();
    for (int off = 1; off < 1024; off <<= 1) {
        int v = (t >= off) ? sums[t - off] : 0;
        __syncthreads();
        if (t >= off) sums[t] += v;
        __syncthreads();
    }
    int run = (t > 0) ? sums[t - 1] : 0;
    for (int i = lo; i < hi; ++i) { rowptr[i] = run; run += cnt[i]; }
    if (t == 0) rowptr[n] = sums[1023];
}

// bin edges by dst, consuming cnt down to 0
__global__ void k_bin(const int* __restrict__ src, const int* __restrict__ dst,
                      int* __restrict__ cnt, const int* __restrict__ rowptr,
                      int* __restrict__ col, int ne) {
    int e = blockIdx.x * blockDim.x + threadIdx.x;
    if (e >= ne) return;
    int t = dst[e];
    int pos = rowptr[t] + atomicSub(&cnt[t], 1) - 1;
    col[pos] = src[e];
}

// Hs0 = dinv * X (elementwise row scale), float4 over n*32
__global__ void k_prescale(const float* __restrict__ X, const float* __restrict__ dinv,
                           float* __restrict__ Hs, int n) {
    int i = blockIdx.x * blockDim.x + threadIdx.x;
    int total = n * (DIM / 4);
    if (i >= total) return;
    int node = i >> 5;
    float w = dinv[node];
    float4 v = ((const float4*)X)[i];
    v.x *= w; v.y *= w; v.z *= w; v.w *= w;
    ((float4*)Hs)[i] = v;
}

// ---------------- pull hop on pre-scaled state ----------------
// Hs'[t] = scale(t) * ( sum_{s in N(t)} Hs[s] + Hs[t] )
// HALF-WAVE (32 lanes x float4 = 512 B) per node: 2 nodes/wave doubles the
// number of independent row-gathers in flight. 4-edge unroll.

__global__ __launch_bounds__(256) void k_pull(const int* __restrict__ rowptr,
                                              const int* __restrict__ col,
                                              const float* __restrict__ dinv,
                                              const float* __restrict__ Hc,
                                              float* __restrict__ Hn, int n, int last) {
    int hw = (blockIdx.x * blockDim.x + threadIdx.x) >> 5;   // half-wave id = node
    if (hw >= n) return;
    int lane = threadIdx.x & 31;
    const float4* __restrict__ base = (const float4*)Hc;
    size_t li = (size_t)hw * 32 + lane;

    float4 acc = base[li];                 // self term
    int e0 = rowptr[hw], e1 = rowptr[hw + 1];
    int e = e0;
    for (; e + 4 <= e1; e += 4) {
        int s0 = col[e], s1 = col[e + 1], s2 = col[e + 2], s3 = col[e + 3];
        float4 a = base[(size_t)s0 * 32 + lane];
        float4 b = base[(size_t)s1 * 32 + lane];
        float4 c = base[(size_t)s2 * 32 + lane];
        float4 d = base[(size_t)s3 * 32 + lane];
        acc.x += (a.x + b.x) + (c.x + d.x);
        acc.y += (a.y + b.y) + (c.y + d.y);
        acc.z += (a.z + b.z) + (c.z + d.z);
        acc.w += (a.w + b.w) + (c.w + d.w);
    }
    for (; e < e1; ++e) {
        int s = col[e];
        float4 a = base[(size_t)s * 32 + lane];
        acc.x += a.x; acc.y += a.y; acc.z += a.z; acc.w += a.w;
    }
    float w = dinv[hw];
    float sc = last ? w : w * w;
    acc.x *= sc; acc.y *= sc; acc.z *= sc; acc.w *= sc;
    ((float4*)Hn)[li] = acc;
}

// ---------------- epilogue: out = H @ W^T + b ----------------
// Block = 32 rows x 64 cols. W-slice in LDS as Wt[jj][d] with +1-float pad
// (33 KiB -> 4 blocks/CU). Lane owns 4 rows x 2 cols; per d4 iter:
// 4 broadcast global b128 (H, register double-buffered) + 2 LDS b128 (W)
// feed 32 FMA.

__global__ __launch_bounds__(256) void k_gemm(const float* __restrict__ H,
                                              const float* __restrict__ W,
                                              const float* __restrict__ b,
                                              float* __restrict__ out, int n) {
    __shared__ float Wt[64][DIM + 1];    // [jj][d], pad -> conflict-light
    int tid = threadIdx.x;
    int jb  = blockIdx.x & 1;            // which 64-col half
    int rb  = blockIdx.x >> 1;           // 32-row tile

    // stage W rows jb*64..jb*64+63 (8192 floats) coalesced, write padded LDS
    const float4* Wv = (const float4*)(W + (size_t)jb * 64 * DIM);
    for (int idx = tid; idx < 64 * 32; idx += 256) {
        int jj = idx >> 5;               // W row within slice
        int dq = idx & 31;               // float4 index along d
        float4 v = Wv[idx];
        *(float4*)&Wt[jj][dq * 4] = v;
    }
    __syncthreads();

    int lane = tid & 63;
    int wv   = tid >> 6;                 // wave 0..3
    int cp   = lane & 31;                // col pair within 64-col slice
    int rg   = lane >> 5;                // row group 0/1
    int j0   = jb * 64 + cp * 2;
    int row0 = rb * 32 + wv * 8 + rg * 4;

    float2 bias = make_float2(b[j0], b[j0 + 1]);
    float2 acc[4];
    const float* hp[4];
    #pragma unroll
    for (int r = 0; r < 4; ++r) {
        acc[r] = bias;
        int rc = row0 + r; if (rc > n - 1) rc = n - 1;   // clamp loads; stores guarded
        hp[r] = H + (size_t)rc * DIM;
    }

    float4 cur[4];
    #pragma unroll
    for (int r = 0; r < 4; ++r) cur[r] = *(const float4*)(hp[r]);

    for (int d4 = 0; d4 < DIM / 4; ++d4) {
        float4 nxt[4];
        if (d4 + 1 < DIM / 4) {
            #pragma unroll
            for (int r = 0; r < 4; ++r) nxt[r] = *(const float4*)(hp[r] + (d4 + 1) * 4);
        }
        float4 wa = *(const float4*)&Wt[cp * 2 + 0][d4 * 4];
        float4 wb = *(const float4*)&Wt[cp * 2 + 1][d4 * 4];
        #pragma unroll
        for (int r = 0; r < 4; ++r) {
            acc[r].x = fmaf(cur[r].x, wa.x, acc[r].x);
            acc[r].y = fmaf(cur[r].x, wb.x, acc[r].y);
            acc[r].x = fmaf(cur[r].y, wa.y, acc[r].x);
            acc[r].y = fmaf(cur[r].y, wb.y, acc[r].y);
            acc[r].x = fmaf(cur[r].z, wa.z, acc[r].x);
            acc[r].y = fmaf(cur[r].z, wb.z, acc[r].y);
            acc[r].x = fmaf(cur[r].w, wa.w, acc[r].x);
            acc[r].y = fmaf(cur[r].w, wb.w, acc[r].y);
        }
        #pragma unroll
        for (int r = 0; r < 4; ++r) cur[r] = nxt[r];
    }

    #pragma unroll
    for (int r = 0; r < 4; ++r) {
        int row = row0 + r;
        if (row < n) *(float2*)(out + (size_t)row * DIM + j0) = acc[r];
    }
}

// ---------------- launch ----------------

extern "C" void kernel_launch(void* const* d_in, const int* in_sizes, int n_in,
                              void* d_out, int out_size, void* d_ws, size_t ws_size,
                              hipStream_t stream) {
    const int*   E = (const int*)d_in[1];
    const float* X = (const float*)d_in[2];
    const float* W = (const float*)d_in[3];
    const float* b = (const float*)d_in[4];

    int n  = in_sizes[0];
    int ne = in_sizes[1] / 2;
    const int* src = E;
    const int* dst = E + ne;

    // workspace layout (bytes)
    char* ws = (char*)d_ws;
    float* dinv   = (float*)(ws + 0);                 // n f32
    int*   cnt    = (int*)  (ws + 262144);            // n i32
    int*   rowptr = (int*)  (ws + 524288);            // n+1 i32
    int*   col    = (int*)  (ws + 786432);            // ne i32
    float* Hws    = (float*)(ws + 3211264);           // n*128 f32 (25.6 MB)
    float* Hout   = (float*)d_out;

    const int T = 256;
    int gN  = (n + T - 1) / T;
    int gE  = (ne + T - 1) / T;
    int gNV = (n * (DIM / 4) + T - 1) / T;
    int gHW = (n * 32 + T - 1) / T;   // half-wave per node

    hipMemsetAsync(cnt, 0, (size_t)n * 4, stream);
    k_count<<<gE, T, 0, stream>>>(dst, cnt, ne);
    k_dinv<<<gN, T, 0, stream>>>(cnt, dinv, n);
    k_scan<<<1, 1024, 0, stream>>>(cnt, rowptr, n);
    k_bin<<<gE, T, 0, stream>>>(src, dst, cnt, rowptr, col, ne);

    // Hs0 = dinv * X  -> Hout; hops alternate Hout/Hws
    k_prescale<<<gNV, T, 0, stream>>>(X, dinv, Hout, n);
    k_pull<<<gHW, T, 0, stream>>>(rowptr, col, dinv, Hout, Hws,  n, 0);
    k_pull<<<gHW, T, 0, stream>>>(rowptr, col, dinv, Hws,  Hout, n, 0);
    k_pull<<<gHW, T, 0, stream>>>(rowptr, col, dinv, Hout, Hws,  n, 1);

    // epilogue: Hout = Hws @ W^T + b   (2 col-halves per 32-row tile)
    k_gemm<<<((n + 31) / 32) * 2, 256, 0, stream>>>(Hws, W, b, Hout, n);
}